// Round 4
// baseline (576.454 us; speedup 1.0000x reference)
//
#include <hip/hip_runtime.h>
#include <math.h>

// Problem constants (B=16, S=2048, H=1024)
#define BATCH 16
#define SEQ   2048
#define HID   1024

// ---------------------------------------------------------------------------
// Kernel W: w2[j] = sum_h v[h] * attn_w[h, 1024+j]  (encoder half only; the
// hidden half contributes a per-batch-row constant that cancels in softmax).
// 64 blocks x 256 threads; block b fully owns columns [b*16, b*16+16) -- no
// inter-block dependency, single dispatch replaces the old A+B pair.
// Thread (g = tid>>4, c = tid&15) accumulates rows g*64..g*64+63 for column
// b*16+c, then an LDS tree reduces the 16 row-groups.
// Block 0 additionally zeroes the softmax ticket counters for kernel S
// (visible to the next dispatch via kernel-boundary release/acquire, same
// mechanism that publishes w2 itself).
// ---------------------------------------------------------------------------
__global__ __launch_bounds__(256) void we_kernel(
    const float* __restrict__ attn_w,
    const float* __restrict__ v,
    float* __restrict__ w2,
    int* __restrict__ cnt)
{
    const int tid = threadIdx.x;
    const int bid = blockIdx.x;

    if (bid == 0 && tid < BATCH)
        cnt[tid] = 0;

    __shared__ float vs[HID];
    __shared__ float red[256];

    for (int i = tid; i < HID; i += 256)
        vs[i] = v[i];
    __syncthreads();

    const int c = tid & 15;    // column within the block's slice
    const int g = tid >> 4;    // row group 0..15 (64 rows each)
    const int j = bid * 16 + c;

    float acc = 0.f;
#pragma unroll 16
    for (int k = 0; k < 64; ++k) {
        const int h = g * 64 + k;
        acc += vs[h] * attn_w[(size_t)h * (2 * HID) + HID + j];
    }
    red[tid] = acc;            // red[g*16 + c]
    __syncthreads();

    if (tid < 128) red[tid] += red[tid + 128];
    __syncthreads();
    if (tid < 64)  red[tid] += red[tid + 64];
    __syncthreads();
    if (tid < 32)  red[tid] += red[tid + 32];
    __syncthreads();
    if (tid < 16)
        w2[bid * 16 + tid] = red[tid] + red[tid + 16];
}

// ---------------------------------------------------------------------------
// Kernel S: scores[row] = enc[row,:] . w2 for row in [0, B*S), with the
// per-batch softmax folded in via a ticket: each block covers 16 rows of one
// batch (128 blocks/batch); the last-finishing block of a batch runs the
// softmax for that batch while other batches' blocks are still streaming.
//
// Scores body: one wave per 4 rows; w2 fragment (16 floats) in VGPRs;
// 4 independent accumulators -> batched __shfl_xor butterfly -> lanes 0..3
// store 4 consecutive scores. grid = 2048 blocks * 256 thr = full occupancy.
// 134 MB encoder stream -> HBM/L3-bound (~20 us floor).
//
// Visibility: writer blocks do stores -> __threadfence() -> __syncthreads()
// -> tid0 atomicAdd (release). Reader block: atomicAdd returns 127 ->
// __threadfence() (acquire) -> __syncthreads() -> read all 2048 scores.
// Each 64B scores line is written wholly by exactly one block, so no other
// XCD's L2 can hold a stale copy of another block's line.
// ---------------------------------------------------------------------------
__global__ __launch_bounds__(256) void scores_softmax_kernel(
    const float* __restrict__ enc,
    const float* __restrict__ w2,
    float* __restrict__ scores,
    int* __restrict__ cnt,
    float* __restrict__ out)
{
    const int tid  = threadIdx.x;
    const int wave = (int)((blockIdx.x * 256 + tid) >> 6); // 0..8191
    const int lane = tid & 63;

    float4 w[4];
#pragma unroll
    for (int c = 0; c < 4; ++c)
        w[c] = ((const float4*)w2)[c * 64 + lane];

    float a0 = 0.f, a1 = 0.f, a2 = 0.f, a3 = 0.f;
    const float4* rp0 = (const float4*)(enc + (size_t)(wave * 4 + 0) * HID);
    const float4* rp1 = (const float4*)(enc + (size_t)(wave * 4 + 1) * HID);
    const float4* rp2 = (const float4*)(enc + (size_t)(wave * 4 + 2) * HID);
    const float4* rp3 = (const float4*)(enc + (size_t)(wave * 4 + 3) * HID);

#pragma unroll
    for (int c = 0; c < 4; ++c) {
        const float4 e0 = rp0[c * 64 + lane];
        const float4 e1 = rp1[c * 64 + lane];
        const float4 e2 = rp2[c * 64 + lane];
        const float4 e3 = rp3[c * 64 + lane];
        a0 += e0.x * w[c].x + e0.y * w[c].y + e0.z * w[c].z + e0.w * w[c].w;
        a1 += e1.x * w[c].x + e1.y * w[c].y + e1.z * w[c].z + e1.w * w[c].w;
        a2 += e2.x * w[c].x + e2.y * w[c].y + e2.z * w[c].z + e2.w * w[c].w;
        a3 += e3.x * w[c].x + e3.y * w[c].y + e3.z * w[c].z + e3.w * w[c].w;
    }

    // Batched wave64 butterfly: 6 rounds, 4 independent chains per round.
#pragma unroll
    for (int off = 32; off > 0; off >>= 1) {
        a0 += __shfl_xor(a0, off, 64);
        a1 += __shfl_xor(a1, off, 64);
        a2 += __shfl_xor(a2, off, 64);
        a3 += __shfl_xor(a3, off, 64);
    }

    if (lane < 4) {
        const float val = (lane == 0) ? a0 : (lane == 1) ? a1
                        : (lane == 2) ? a2 : a3;
        scores[wave * 4 + lane] = val;   // 4 consecutive floats, one 16B line
    }

    // ---- ticket: last block of this batch runs the softmax ----------------
    __threadfence();          // release this block's score stores (device)
    __syncthreads();          // all waves' fences done before the ticket

    __shared__ int lastFlag;
    __shared__ float red[256];
    const int b = blockIdx.x >> 7;           // 128 blocks per batch
    if (tid == 0) {
        const int t = atomicAdd(&cnt[b], 1);
        lastFlag = (t == 127);
        if (t == 127) __threadfence();       // acquire others' stores
    }
    __syncthreads();
    if (!lastFlag) return;

    // softmax for batch b (identical numerics to the verified kernel D)
    const float* s = scores + (size_t)b * SEQ;

    float local[8];
    float m = -INFINITY;
#pragma unroll
    for (int i = 0; i < 8; ++i) {
        local[i] = s[tid + i * 256];
        m = fmaxf(m, local[i]);
    }
    red[tid] = m;
    __syncthreads();
    for (int st = 128; st > 0; st >>= 1) {
        if (tid < st) red[tid] = fmaxf(red[tid], red[tid + st]);
        __syncthreads();
    }
    m = red[0];
    __syncthreads();

    float e[8];
    float sum = 0.f;
#pragma unroll
    for (int i = 0; i < 8; ++i) {
        e[i] = __expf(local[i] - m);
        sum += e[i];
    }
    red[tid] = sum;
    __syncthreads();
    for (int st = 128; st > 0; st >>= 1) {
        if (tid < st) red[tid] += red[tid + st];
        __syncthreads();
    }
    const float inv = 1.f / red[0];
#pragma unroll
    for (int i = 0; i < 8; ++i)
        out[(size_t)b * SEQ + tid + i * 256] = e[i] * inv;
}

// ---------------------------------------------------------------------------
// Launch.  Inputs (fp32): hidden[16384], encoder_outputs[33554432],
// attn_w[2097152], attn_b[1024], v[1024].  Output: fp32 [16*2048].
// hidden & attn_b are provably unused (per-row constants cancel in softmax).
//
// ws layout (floats): [0,1024)=w2 | [1024,1040)=cnt (16 ints) |
//                     [132096,164864)=scores   (layout kept from verified ver.)
// ---------------------------------------------------------------------------
extern "C" void kernel_launch(void* const* d_in, const int* in_sizes, int n_in,
                              void* d_out, int out_size, void* d_ws, size_t ws_size,
                              hipStream_t stream)
{
    const float* enc    = (const float*)d_in[1];
    const float* attn_w = (const float*)d_in[2];
    const float* v      = (const float*)d_in[4];

    float* ws     = (float*)d_ws;
    float* w2     = ws;
    int*   cnt    = (int*)(ws + HID);
    float* scores = ws + HID + 128 * HID;

    we_kernel            <<<64,   256, 0, stream>>>(attn_w, v, w2, cnt);
    scores_softmax_kernel<<<2048, 256, 0, stream>>>(enc, w2, scores, cnt,
                                                    (float*)d_out);
}

// Round 5
// 211.479 us; speedup vs baseline: 2.7258x; 2.7258x over previous
//
#include <hip/hip_runtime.h>
#include <math.h>

// Problem constants (B=16, S=2048, H=1024)
#define BATCH 16
#define SEQ   2048
#define HID   1024

// ---------------------------------------------------------------------------
// Kernel W (single dispatch, replaces old A+B pair):
// w2[j] = sum_h v[h] * attn_w[h, 1024+j]  (encoder half only; the hidden half
// contributes a per-batch-row constant that cancels in softmax).
// 64 blocks x 256 threads; block b fully owns columns [b*16, b*16+16) -- no
// inter-block dependency. Thread (g = tid>>4, c = tid&15) accumulates rows
// g*64..g*64+63 for column b*16+c, then an LDS tree reduces the 16 groups.
// Harness-verified in round 4 (absmax 2.384e-7).
// ---------------------------------------------------------------------------
__global__ __launch_bounds__(256) void we_kernel(
    const float* __restrict__ attn_w,
    const float* __restrict__ v,
    float* __restrict__ w2)
{
    const int tid = threadIdx.x;
    const int bid = blockIdx.x;

    __shared__ float vs[HID];
    __shared__ float red[256];

    for (int i = tid; i < HID; i += 256)
        vs[i] = v[i];
    __syncthreads();

    const int c = tid & 15;    // column within the block's slice
    const int g = tid >> 4;    // row group 0..15 (64 rows each)
    const int j = bid * 16 + c;

    float acc = 0.f;
#pragma unroll 16
    for (int k = 0; k < 64; ++k) {
        const int h = g * 64 + k;
        acc += vs[h] * attn_w[(size_t)h * (2 * HID) + HID + j];
    }
    red[tid] = acc;            // red[g*16 + c]
    __syncthreads();

    if (tid < 128) red[tid] += red[tid + 128];
    __syncthreads();
    if (tid < 64)  red[tid] += red[tid + 64];
    __syncthreads();
    if (tid < 32)  red[tid] += red[tid + 32];
    __syncthreads();
    if (tid < 16)
        w2[bid * 16 + tid] = red[tid] + red[tid + 16];
}

// ---------------------------------------------------------------------------
// Kernel C (dominant): scores[row] = enc[row,:] . w2   for row in [0, B*S).
// One wave per 4 rows; lane l covers elements {c*256 + l*4 .. +3 | c<4}.
// w2 fragment (16 floats) preloaded into VGPRs, amortized over 4 rows.
// 4 independent accumulators -> batched __shfl_xor butterfly (6 rounds x 4
// independent chains) -> lanes 0..3 store 4 consecutive scores (coalesced).
// grid = 2048 blocks * 256 thr = 8192 waves = 32 waves/CU.
// 134 MB encoder stream -> HBM/L3-bound (~20 us floor). Verified round 3.
// NO cross-block sync of any kind (rounds 2 & 4 proved grid.sync /
// threadfence tickets cost 300-400 us on this chip).
// ---------------------------------------------------------------------------
__global__ __launch_bounds__(256) void scores_kernel(
    const float* __restrict__ enc,
    const float* __restrict__ w2,
    float* __restrict__ scores)
{
    const int wave = (int)((blockIdx.x * 256 + threadIdx.x) >> 6); // 0..8191
    const int lane = threadIdx.x & 63;

    float4 w[4];
#pragma unroll
    for (int c = 0; c < 4; ++c)
        w[c] = ((const float4*)w2)[c * 64 + lane];

    float a0 = 0.f, a1 = 0.f, a2 = 0.f, a3 = 0.f;
    const float4* rp0 = (const float4*)(enc + (size_t)(wave * 4 + 0) * HID);
    const float4* rp1 = (const float4*)(enc + (size_t)(wave * 4 + 1) * HID);
    const float4* rp2 = (const float4*)(enc + (size_t)(wave * 4 + 2) * HID);
    const float4* rp3 = (const float4*)(enc + (size_t)(wave * 4 + 3) * HID);

#pragma unroll
    for (int c = 0; c < 4; ++c) {
        const float4 e0 = rp0[c * 64 + lane];
        const float4 e1 = rp1[c * 64 + lane];
        const float4 e2 = rp2[c * 64 + lane];
        const float4 e3 = rp3[c * 64 + lane];
        a0 += e0.x * w[c].x + e0.y * w[c].y + e0.z * w[c].z + e0.w * w[c].w;
        a1 += e1.x * w[c].x + e1.y * w[c].y + e1.z * w[c].z + e1.w * w[c].w;
        a2 += e2.x * w[c].x + e2.y * w[c].y + e2.z * w[c].z + e2.w * w[c].w;
        a3 += e3.x * w[c].x + e3.y * w[c].y + e3.z * w[c].z + e3.w * w[c].w;
    }

#pragma unroll
    for (int off = 32; off > 0; off >>= 1) {
        a0 += __shfl_xor(a0, off, 64);
        a1 += __shfl_xor(a1, off, 64);
        a2 += __shfl_xor(a2, off, 64);
        a3 += __shfl_xor(a3, off, 64);
    }

    if (lane < 4) {
        const float val = (lane == 0) ? a0 : (lane == 1) ? a1
                        : (lane == 2) ? a2 : a3;
        scores[wave * 4 + lane] = val;   // 4 consecutive floats, one 16B line
    }
}

// ---------------------------------------------------------------------------
// Kernel D: row softmax over [BATCH, SEQ]. One block per batch row.
// v2: wave-shuffle reductions (2 barriers instead of 16).
// 256 threads = 4 waves; each thread owns 8 elements.
// ---------------------------------------------------------------------------
__global__ __launch_bounds__(256) void softmax_kernel(
    const float* __restrict__ scores,
    float* __restrict__ out)
{
    const int b    = blockIdx.x;
    const int tid  = threadIdx.x;
    const int lane = tid & 63;
    const int wv   = tid >> 6;               // 0..3
    const float* s = scores + (size_t)b * SEQ;

    __shared__ float redm[4];
    __shared__ float reds[4];

    float local[8];
    float m = -INFINITY;
#pragma unroll
    for (int i = 0; i < 8; ++i) {
        local[i] = s[tid + i * 256];
        m = fmaxf(m, local[i]);
    }
#pragma unroll
    for (int off = 32; off > 0; off >>= 1)
        m = fmaxf(m, __shfl_xor(m, off, 64));
    if (lane == 0) redm[wv] = m;
    __syncthreads();
    m = fmaxf(fmaxf(redm[0], redm[1]), fmaxf(redm[2], redm[3]));

    float e[8];
    float sum = 0.f;
#pragma unroll
    for (int i = 0; i < 8; ++i) {
        e[i] = __expf(local[i] - m);
        sum += e[i];
    }
#pragma unroll
    for (int off = 32; off > 0; off >>= 1)
        sum += __shfl_xor(sum, off, 64);
    if (lane == 0) reds[wv] = sum;
    __syncthreads();
    sum = reds[0] + reds[1] + reds[2] + reds[3];

    const float inv = 1.f / sum;
#pragma unroll
    for (int i = 0; i < 8; ++i)
        out[(size_t)b * SEQ + tid + i * 256] = e[i] * inv;
}

// ---------------------------------------------------------------------------
// Launch.  Inputs (fp32): hidden[16384], encoder_outputs[33554432],
// attn_w[2097152], attn_b[1024], v[1024].  Output: fp32 [16*2048].
// hidden & attn_b are provably unused (per-row constants cancel in softmax).
//
// ws layout (floats): [0,1024)=w2 | [132096,164864)=scores
// ---------------------------------------------------------------------------
extern "C" void kernel_launch(void* const* d_in, const int* in_sizes, int n_in,
                              void* d_out, int out_size, void* d_ws, size_t ws_size,
                              hipStream_t stream)
{
    const float* enc    = (const float*)d_in[1];
    const float* attn_w = (const float*)d_in[2];
    const float* v      = (const float*)d_in[4];

    float* ws     = (float*)d_ws;
    float* w2     = ws;
    float* scores = ws + HID + 128 * HID;

    we_kernel     <<<64,    256, 0, stream>>>(attn_w, v, w2);
    scores_kernel <<<2048,  256, 0, stream>>>(enc, w2, scores);
    softmax_kernel<<<BATCH, 256, 0, stream>>>(scores, (float*)d_out);
}